// Round 20
// baseline (470.407 us; speedup 1.0000x reference)
//
#include <hip/hip_runtime.h>
#include <hip/hip_bf16.h>

#define N_NODES 16384
#define E_EDGES 262144
#define IN_DIM 512

// fixed-point scale for deterministic aggregation
#define AGG_SCALE 1099511627776.0   // 2^40
#define AGG_INV   (1.0/1099511627776.0)

typedef __attribute__((ext_vector_type(8))) short bf16x8;
typedef __attribute__((ext_vector_type(4))) float f32x4;

// ---------------- inline edge dtype detection (per-wave uniform) ----------------
__device__ __forceinline__ int detect64(const void* __restrict__ ei) {
    const unsigned long long v = ((const unsigned long long*)ei)[threadIdx.x & 63];
    return __all(v < 16384ull) ? 1 : 0;
}

__device__ __forceinline__ int edge_at(const void* __restrict__ ei, int is64, int pos) {
    return is64 ? (int)(((const long long*)ei)[pos]) : ((const int*)ei)[pos];
}

// ---------------- degree ----------------
__global__ __launch_bounds__(256) void deg_kernel(const void* __restrict__ ei,
                                                  int* __restrict__ deg) {
    const int is64 = detect64(ei);
    int e = blockIdx.x * 256 + threadIdx.x;
    int r = edge_at(ei, is64, e);
    if (r >= 0 && r < N_NODES) atomicAdd(&deg[r], 1);
}

// ---------------- exclusive prefix scan of deg -> offs; also dinv (fused) ----------------
__global__ __launch_bounds__(256) void scan_kernel(const int* __restrict__ deg, int* __restrict__ offs,
                                                   float* __restrict__ dinv) {
    __shared__ int part[257];
    const int t = threadIdx.x;
    const int base = t * 64;
    int s = 0;
    #pragma unroll 4
    for (int i = 0; i < 64; ++i) s += deg[base + i];
    part[t + 1] = s;
    if (t == 0) part[0] = 0;
    __syncthreads();
    if (t == 0) {
        int acc = 0;
        for (int i = 1; i <= 256; ++i) { acc += part[i]; part[i] = acc; }
    }
    __syncthreads();
    int run = part[t];                      // exclusive offset of chunk t
    for (int i = 0; i < 64; ++i) {
        const int d = deg[base + i];
        offs[base + i] = run; run += d;
        dinv[base + i] = (d > 0) ? __fdiv_rn(1.0f, __fsqrt_rn((float)d)) : 0.0f;
    }
    if (t == 255) offs[N_NODES] = run;
}

// ---------------- scatter edges into CSR slots ----------------
__global__ __launch_bounds__(256) void scatter_kernel(
    const void* __restrict__ ei,
    const int* __restrict__ offs, int* __restrict__ cursor, int* __restrict__ ecol_s)
{
    const int is64 = detect64(ei);
    int e = blockIdx.x * 256 + threadIdx.x;
    int r  = edge_at(ei, is64, e);
    if (r < 0 || r >= N_NODES) return;
    int cc = edge_at(ei, is64, E_EDGES + e);
    int pos = atomicAdd(&cursor[r], 1);
    ecol_s[offs[r] + pos] = (cc >= 0 && cc < N_NODES) ? cc : -1;
}

// ---------------- MLP: f32, k-ascending single-accumulator fmaf chains ----------------
__device__ __forceinline__ void dense_layer32(float (*hsw)[64], int c,
                                              const float* __restrict__ WP,
                                              const float* __restrict__ BP,
                                              bool relu, bool last,
                                              float* __restrict__ gout, int n0)
{
    float s0 = 0.0f, s1 = 0.0f, s2 = 0.0f, s3 = 0.0f;
    #pragma unroll 4
    for (int k = 0; k < 64; k += 4) {
        const float4 h0 = *(const float4*)&hsw[0][k];
        const float4 h1 = *(const float4*)&hsw[1][k];
        const float4 h2 = *(const float4*)&hsw[2][k];
        const float4 h3 = *(const float4*)&hsw[3][k];
        const float w0 = WP[k * 64 + c];
        const float w1 = WP[(k + 1) * 64 + c];
        const float w2 = WP[(k + 2) * 64 + c];
        const float w3 = WP[(k + 3) * 64 + c];
        s0 = fmaf(h0.x, w0, s0); s0 = fmaf(h0.y, w1, s0); s0 = fmaf(h0.z, w2, s0); s0 = fmaf(h0.w, w3, s0);
        s1 = fmaf(h1.x, w0, s1); s1 = fmaf(h1.y, w1, s1); s1 = fmaf(h1.z, w2, s1); s1 = fmaf(h1.w, w3, s1);
        s2 = fmaf(h2.x, w0, s2); s2 = fmaf(h2.y, w1, s2); s2 = fmaf(h2.z, w2, s2); s2 = fmaf(h2.w, w3, s2);
        s3 = fmaf(h3.x, w0, s3); s3 = fmaf(h3.y, w1, s3); s3 = fmaf(h3.z, w2, s3); s3 = fmaf(h3.w, w3, s3);
    }
    const float bv = BP[c];
    s0 += bv; s1 += bv; s2 += bv; s3 += bv;
    if (relu) { s0 = fmaxf(s0, 0.0f); s1 = fmaxf(s1, 0.0f); s2 = fmaxf(s2, 0.0f); s3 = fmaxf(s3, 0.0f); }
    __syncthreads();
    if (last) {
        gout[(size_t)(n0 + 0) * 64 + c] = s0;
        gout[(size_t)(n0 + 1) * 64 + c] = s1;
        gout[(size_t)(n0 + 2) * 64 + c] = s2;
        gout[(size_t)(n0 + 3) * 64 + c] = s3;
    } else {
        hsw[0][c] = s0; hsw[1][c] = s1; hsw[2][c] = s2; hsw[3][c] = s3;
    }
    __syncthreads();
}

__global__ __launch_bounds__(256) void mlp_kernel(
    const float* __restrict__ x,
    const float* __restrict__ W1, const float* __restrict__ b1,
    const float* __restrict__ W2, const float* __restrict__ b2,
    const float* __restrict__ W3, const float* __restrict__ b3,
    const float* __restrict__ W4, const float* __restrict__ b4,
    const float* __restrict__ Wg1, const float* __restrict__ bg1,
    const float* __restrict__ Wg2, const float* __restrict__ bg2,
    float* __restrict__ g32)
{
    __shared__ float hs[4][4][64];
    const int w = threadIdx.x >> 6;
    const int c = threadIdx.x & 63;
    const int n0 = blockIdx.x * 16 + w * 4;

    float a0 = 0.0f, a1 = 0.0f, a2 = 0.0f, a3 = 0.0f;
    const float* xp = x + (size_t)n0 * IN_DIM;
    #pragma unroll 2
    for (int k = 0; k < IN_DIM; k += 4) {
        const float4 x0 = *(const float4*)(xp + k);
        const float4 x1 = *(const float4*)(xp + IN_DIM + k);
        const float4 x2 = *(const float4*)(xp + 2 * IN_DIM + k);
        const float4 x3 = *(const float4*)(xp + 3 * IN_DIM + k);
        const float w0 = W1[k * 64 + c];
        const float w1 = W1[(k + 1) * 64 + c];
        const float w2 = W1[(k + 2) * 64 + c];
        const float w3 = W1[(k + 3) * 64 + c];
        a0 = fmaf(x0.x, w0, a0); a0 = fmaf(x0.y, w1, a0); a0 = fmaf(x0.z, w2, a0); a0 = fmaf(x0.w, w3, a0);
        a1 = fmaf(x1.x, w0, a1); a1 = fmaf(x1.y, w1, a1); a1 = fmaf(x1.z, w2, a1); a1 = fmaf(x1.w, w3, a1);
        a2 = fmaf(x2.x, w0, a2); a2 = fmaf(x2.y, w1, a2); a2 = fmaf(x2.z, w2, a2); a2 = fmaf(x2.w, w3, a2);
        a3 = fmaf(x3.x, w0, a3); a3 = fmaf(x3.y, w1, a3); a3 = fmaf(x3.z, w2, a3); a3 = fmaf(x3.w, w3, a3);
    }
    const float bv = b1[c];
    hs[w][0][c] = fmaxf(a0 + bv, 0.0f);
    hs[w][1][c] = fmaxf(a1 + bv, 0.0f);
    hs[w][2][c] = fmaxf(a2 + bv, 0.0f);
    hs[w][3][c] = fmaxf(a3 + bv, 0.0f);
    __syncthreads();

    dense_layer32(hs[w], c, W2, b2, false, false, g32, n0);
    dense_layer32(hs[w], c, W3, b3, true,  false, g32, n0);
    dense_layer32(hs[w], c, W4, b4, false, false, g32, n0);
    dense_layer32(hs[w], c, Wg1, bg1, true, false, g32, n0);
    dense_layer32(hs[w], c, Wg2, bg2, false, true, g32, n0);
}

// ---------------- CSR aggregation + finalize (fused): one wave per row ----------------
__global__ __launch_bounds__(256) void aggcsr_kernel(
    const int* __restrict__ offs, const int* __restrict__ ecol_s,
    const float* __restrict__ dinv, const float* __restrict__ g32,
    float* __restrict__ F32, short* __restrict__ Fb)
{
    const int r = (blockIdx.x << 2) + (threadIdx.x >> 6);
    const int h = threadIdx.x & 63;
    const float dr = dinv[r];
    const int b = offs[r], e2 = offs[r + 1];
    long long sum = 0;
    #pragma unroll 8
    for (int i = b; i < e2; ++i) {
        const int cc = ecol_s[i];
        if (cc < 0) continue;
        const float m = __fmul_rn(__fmul_rn(dr, dinv[cc]), g32[((size_t)cc << 6) + h]);
        sum += __double2ll_rn((double)m * AGG_SCALE);
    }
    const float a = (float)((double)sum * AGG_INV);
    const int idx = (r << 6) + h;
    const float f = g32[idx] - a;
    F32[idx] = f;
    __hip_bfloat16 hb = __float2bfloat16(f);
    Fb[idx] = *(short*)&hb;
}

// ---------------- MFMA bf16 screening: LDS-staged B panel, single-barrier pipeline ----------------
__device__ __forceinline__ void ins6(unsigned* k, unsigned x) {
    const unsigned r0 = max(k[0], x);
    k[5] = min(k[4], max(k[5], x));
    k[4] = min(k[3], max(k[4], x));
    k[3] = min(k[2], max(k[3], x));
    k[2] = min(k[1], max(k[2], x));
    k[1] = min(k[0], max(k[1], x));
    k[0] = r0;
}

__global__ __launch_bounds__(256) void screen_kernel(
    const short* __restrict__ Fb, int* __restrict__ cand)
{
    __shared__ short Bt[2][128 * 64];   // 2 x 16 KB: [buf][col*64 + swizzled k]
    const int l = threadIdx.x & 63;
    const int w = threadIdx.x >> 6;
    const int rb = blockIdx.x >> 1;
    const int sp = blockIdx.x & 1;
    const int r0 = rb * 64 + w * 16;
    const int c0 = sp * 8192;

    // A fragments: lane l <- Fb[r0 + (l&15)][8*(l>>4) .. +7] and +32
    const short* ap = Fb + ((size_t)(r0 + (l & 15)) << 6) + ((l >> 4) << 3);
    const bf16x8 a0 = *(const bf16x8*)(ap);
    const bf16x8 a1 = *(const bf16x8*)(ap + 32);

    unsigned keys[4][6];
    #pragma unroll
    for (int r = 0; r < 4; ++r)
        #pragma unroll
        for (int t = 0; t < 6; ++t) keys[r][t] = 0u;

    // staging role: col = tid&127, granules jb..jb+3 (64B of the 128B row)
    const int scol = threadIdx.x & 127;
    const int jb = (threadIdx.x >> 7) * 4;
    const short* gsrc0 = Fb + ((size_t)(c0 + scol) << 6) + jb * 8;

    // prologue: stage tile 0; preload tile 1 into st
    bf16x8 st[4];
    #pragma unroll
    for (int j = 0; j < 4; ++j) st[j] = *(const bf16x8*)(gsrc0 + j * 8);
    #pragma unroll
    for (int j = 0; j < 4; ++j)
        *(bf16x8*)(&Bt[0][scol * 64 + (((jb + j) ^ (scol & 7)) << 3)]) = st[j];
    #pragma unroll
    for (int j = 0; j < 4; ++j) st[j] = *(const bf16x8*)(gsrc0 + (1 << 13) + j * 8);
    __syncthreads();

    const unsigned invb = 0x80000000u | (unsigned)(16383 - c0 - (l & 15));
    const int g0 = (l >> 4) ^ (l & 7);
    const int g1 = ((l >> 4) + 4) ^ (l & 7);
    int cur = 0;

    #pragma unroll 1
    for (int t = 0; t < 64; ++t) {
        const short* B = &Bt[cur][0];
        bf16x8 bf[16];
        #pragma unroll
        for (int s = 0; s < 8; ++s) {
            const int C = s * 16 + (l & 15);
            bf[2 * s]     = *(const bf16x8*)(B + C * 64 + (g0 << 3));
            bf[2 * s + 1] = *(const bf16x8*)(B + C * 64 + (g1 << 3));
        }
        if (t + 1 < 64) {
            #pragma unroll
            for (int j = 0; j < 4; ++j)
                *(bf16x8*)(&Bt[cur ^ 1][scol * 64 + (((jb + j) ^ (scol & 7)) << 3)]) = st[j];
        }
        if (t + 2 < 64) {
            const short* gs = gsrc0 + ((size_t)(t + 2) << 13);
            #pragma unroll
            for (int j = 0; j < 4; ++j) st[j] = *(const bf16x8*)(gs + j * 8);
        }
        #pragma unroll
        for (int s = 0; s < 8; ++s) {
            f32x4 acc = {0.0f, 0.0f, 0.0f, 0.0f};
            acc = __builtin_amdgcn_mfma_f32_16x16x32_bf16(a0, bf[2 * s], acc, 0, 0, 0);
            acc = __builtin_amdgcn_mfma_f32_16x16x32_bf16(a1, bf[2 * s + 1], acc, 0, 0, 0);
            const unsigned xv = invb - (unsigned)((t << 7) + (s << 4));
            #pragma unroll
            for (int r = 0; r < 4; ++r) {
                const unsigned key = (__float_as_uint(acc[r]) & 0xFFFFC000u) ^ xv;
                ins6(keys[r], key);
            }
        }
        __syncthreads();   // reads of cur done AND write of cur^1 done
        cur ^= 1;
    }

    #pragma unroll
    for (int r = 0; r < 4; ++r) {
        const int row = r0 + ((l >> 4) << 2) + r;
        int* cp = cand + ((size_t)(sp * N_NODES + row)) * 96 + (l & 15) * 6;
        #pragma unroll
        for (int t = 0; t < 6; ++t) cp[t] = 16383 - (int)(keys[r][t] & 0x3FFFu);
    }
}

// ---------------- refine2: grid-stride (8 rows/block) b128-LDS staged exact recompute ----------------
// Dispatch-amortized: 2048 blocks instead of 16384. Merge of row i overlaps staging of
// row i+1 (merge reads sval/sidx only; scand's prior readers finished at the mid barrier).
__global__ __launch_bounds__(512) void refine2_kernel(
    const float* __restrict__ F, const int* __restrict__ cand,
    float* __restrict__ out)
{
    __shared__ float scand[192 * 68];   // 52224 B, 16B-aligned rows (stride 68)
    __shared__ float sval[192];
    __shared__ int   sidx[192];
    const int t = threadIdx.x;
    const int g = t >> 4, qq = t & 15;   // stage role: g in 0..31

    #pragma unroll 1
    for (int row = blockIdx.x; row < N_NODES; row += 2048) {
        // stage 192 candidate rows: 32 groups x 6 slots, 16 threads x float4 = 256B per row
        int cidx6[6];
        #pragma unroll
        for (int i = 0; i < 6; ++i) {
            const int s = i * 32 + g;
            const int sp = (s >= 96) ? 1 : 0;
            const int slot = s - 96 * sp;
            cidx6[i] = cand[((size_t)(sp * N_NODES + row)) * 96 + slot];
        }
        float4 v6[6];
        #pragma unroll
        for (int i = 0; i < 6; ++i)
            v6[i] = *(const float4*)(F + ((size_t)cidx6[i] << 6) + (qq << 2));
        #pragma unroll
        for (int i = 0; i < 6; ++i)
            *(float4*)(&scand[(i * 32 + g) * 68 + (qq << 2)]) = v6[i];
        __syncthreads();   // staging done; also completes previous row's merge

        if (t < 192) {
            const int sp = (t >= 96) ? 1 : 0;
            const int slot = t - 96 * sp;
            const int c = cand[((size_t)(sp * N_NODES + row)) * 96 + slot];
            const float* fp = &scand[t * 68];
            const float* frp = F + ((size_t)row << 6);
            float acc = 0.0f;
            #pragma unroll 4
            for (int j = 0; j < 16; ++j) {
                const float4 a = *(const float4*)(frp + 4 * j);   // L1-broadcast global
                const float4 b = *(const float4*)(fp + 4 * j);    // ds_read_b128
                acc = fmaf(a.x, b.x, acc);
                acc = fmaf(a.y, b.y, acc);
                acc = fmaf(a.z, b.z, acc);
                acc = fmaf(a.w, b.w, acc);
            }
            sval[t] = acc; sidx[t] = c;
        }
        __syncthreads();   // scand free for next row's staging; sval ready for merge

        if (t < 64) {
            float v0 = sval[t], v1 = sval[t + 64], v2 = sval[t + 128];
            int   i0 = sidx[t], i1 = sidx[t + 64], i2 = sidx[t + 128];
            #pragma unroll 1
            for (int it = 0; it < 8; ++it) {
                float bv = v0; int bi = i0;
                if (v1 > bv || (v1 == bv && i1 < bi)) { bv = v1; bi = i1; }
                if (v2 > bv || (v2 == bv && i2 < bi)) { bv = v2; bi = i2; }
                #pragma unroll
                for (int off = 32; off > 0; off >>= 1) {
                    float ov = __shfl_xor(bv, off);
                    int   oi = __shfl_xor(bi, off);
                    if (ov > bv || (ov == bv && oi < bi)) { bv = ov; bi = oi; }
                }
                if (t == 0) {
                    out[(size_t)row * 8 + it]          = bv;          // topk_vals
                    out[131072 + (size_t)row * 8 + it] = (float)row;  // new_edge_index row 0
                    out[262144 + (size_t)row * 8 + it] = (float)bi;   // new_edge_index row 1
                }
                if (i0 == bi) v0 = -3.4e38f;   // cols distinct per row
                if (i1 == bi) v1 = -3.4e38f;
                if (i2 == bi) v2 = -3.4e38f;
            }
        }
        // no barrier here: next iteration's post-stage barrier orders merge vs sval overwrite
    }
}

__global__ void canary_kernel(float* out, float code) {
    out[0] = code;
}

// ---------------- launch ----------------
extern "C" void kernel_launch(void* const* d_in, const int* in_sizes, int n_in,
                              void* d_out, int out_size, void* d_ws, size_t ws_size,
                              hipStream_t stream)
{
    const float* x   = (const float*)d_in[0];
    const void*  ei  = d_in[1];
    const float* W1  = (const float*)d_in[2];  const float* b1  = (const float*)d_in[3];
    const float* W2  = (const float*)d_in[4];  const float* b2  = (const float*)d_in[5];
    const float* W3  = (const float*)d_in[6];  const float* b3  = (const float*)d_in[7];
    const float* W4  = (const float*)d_in[8];  const float* b4  = (const float*)d_in[9];
    const float* Wg1 = (const float*)d_in[10]; const float* bg1 = (const float*)d_in[11];
    const float* Wg2 = (const float*)d_in[12]; const float* bg2 = (const float*)d_in[13];
    float* out = (float*)d_out;

    // workspace layout (stream-ordered overlays):
    //   g32   [0, 4M)
    //   F32   [4M, 8M)
    //   Fb    [8M, 10M)
    //   cand  [10M, 22M)  -- first 1.1M overlaid by CSR scratch (dead before screen):
    //       ecol_s [10M, 11M), offs [11M, +68K)
    //   deg [23M, +64K) cursor [23M+64K, +128K) (single memset) dinv [23M+128K, +192K)
    char* ws = (char*)d_ws;
    float* g32 = (float*)(ws);
    float* F32 = (float*)(ws + ((size_t)4 << 20));
    short* Fb  = (short*)(ws + ((size_t)8 << 20));
    int*   cand   = (int*)(ws + ((size_t)10 << 20));
    int*   ecol_s = (int*)(ws + ((size_t)10 << 20));
    int*   offs   = (int*)(ws + ((size_t)11 << 20));
    int*   deg    = (int*)(ws + ((size_t)23 << 20));
    int*   cursor = (int*)(ws + ((size_t)23 << 20) + (1u << 16));
    float* dinvf  = (float*)(ws + ((size_t)23 << 20) + (2u << 16));

    const size_t NEEDED = ((size_t)23 << 20) + (3u << 16);
    if (ws_size < NEEDED || n_in < 14) {
        canary_kernel<<<1, 1, 0, stream>>>(out, ws_size < NEEDED ? 5000.0f : 3000.0f);
        return;
    }

    hipMemsetAsync(deg, 0, 2 * N_NODES * sizeof(int), stream);   // deg + cursor (adjacent)

    deg_kernel<<<E_EDGES / 256, 256, 0, stream>>>(ei, deg);
    scan_kernel<<<1, 256, 0, stream>>>(deg, offs, dinvf);
    scatter_kernel<<<E_EDGES / 256, 256, 0, stream>>>(ei, offs, cursor, ecol_s);
    mlp_kernel<<<N_NODES / 16, 256, 0, stream>>>(x, W1, b1, W2, b2, W3, b3, W4, b4, Wg1, bg1, Wg2, bg2, g32);
    aggcsr_kernel<<<N_NODES / 4, 256, 0, stream>>>(offs, ecol_s, dinvf, g32, F32, Fb);
    screen_kernel<<<512, 256, 0, stream>>>(Fb, cand);
    refine2_kernel<<<2048, 512, 0, stream>>>(F32, cand, out);
}

// Round 21
// 447.396 us; speedup vs baseline: 1.0514x; 1.0514x over previous
//
#include <hip/hip_runtime.h>
#include <hip/hip_bf16.h>

#define N_NODES 16384
#define E_EDGES 262144
#define IN_DIM 512
#define KKEEP 56

// fixed-point scale for deterministic aggregation
#define AGG_SCALE 1099511627776.0   // 2^40
#define AGG_INV   (1.0/1099511627776.0)

typedef __attribute__((ext_vector_type(8))) short bf16x8;
typedef __attribute__((ext_vector_type(4))) float f32x4;

// ---------------- inline edge dtype detection (per-wave uniform) ----------------
__device__ __forceinline__ int detect64(const void* __restrict__ ei) {
    const unsigned long long v = ((const unsigned long long*)ei)[threadIdx.x & 63];
    return __all(v < 16384ull) ? 1 : 0;
}

__device__ __forceinline__ int edge_at(const void* __restrict__ ei, int is64, int pos) {
    return is64 ? (int)(((const long long*)ei)[pos]) : ((const int*)ei)[pos];
}

// ---------------- degree ----------------
__global__ __launch_bounds__(256) void deg_kernel(const void* __restrict__ ei,
                                                  int* __restrict__ deg) {
    const int is64 = detect64(ei);
    int e = blockIdx.x * 256 + threadIdx.x;
    int r = edge_at(ei, is64, e);
    if (r >= 0 && r < N_NODES) atomicAdd(&deg[r], 1);
}

// ---------------- exclusive prefix scan of deg -> offs; also dinv (fused) ----------------
__global__ __launch_bounds__(256) void scan_kernel(const int* __restrict__ deg, int* __restrict__ offs,
                                                   float* __restrict__ dinv) {
    __shared__ int part[257];
    const int t = threadIdx.x;
    const int base = t * 64;
    int s = 0;
    #pragma unroll 4
    for (int i = 0; i < 64; ++i) s += deg[base + i];
    part[t + 1] = s;
    if (t == 0) part[0] = 0;
    __syncthreads();
    if (t == 0) {
        int acc = 0;
        for (int i = 1; i <= 256; ++i) { acc += part[i]; part[i] = acc; }
    }
    __syncthreads();
    int run = part[t];                      // exclusive offset of chunk t
    for (int i = 0; i < 64; ++i) {
        const int d = deg[base + i];
        offs[base + i] = run; run += d;
        dinv[base + i] = (d > 0) ? __fdiv_rn(1.0f, __fsqrt_rn((float)d)) : 0.0f;
    }
    if (t == 255) offs[N_NODES] = run;
}

// ---------------- scatter edges into CSR slots ----------------
__global__ __launch_bounds__(256) void scatter_kernel(
    const void* __restrict__ ei,
    const int* __restrict__ offs, int* __restrict__ cursor, int* __restrict__ ecol_s)
{
    const int is64 = detect64(ei);
    int e = blockIdx.x * 256 + threadIdx.x;
    int r  = edge_at(ei, is64, e);
    if (r < 0 || r >= N_NODES) return;
    int cc = edge_at(ei, is64, E_EDGES + e);
    int pos = atomicAdd(&cursor[r], 1);
    ecol_s[offs[r] + pos] = (cc >= 0 && cc < N_NODES) ? cc : -1;
}

// ---------------- MLP: f32, k-ascending single-accumulator fmaf chains ----------------
__device__ __forceinline__ void dense_layer32(float (*hsw)[64], int c,
                                              const float* __restrict__ WP,
                                              const float* __restrict__ BP,
                                              bool relu, bool last,
                                              float* __restrict__ gout, int n0)
{
    float s0 = 0.0f, s1 = 0.0f, s2 = 0.0f, s3 = 0.0f;
    #pragma unroll 4
    for (int k = 0; k < 64; k += 4) {
        const float4 h0 = *(const float4*)&hsw[0][k];
        const float4 h1 = *(const float4*)&hsw[1][k];
        const float4 h2 = *(const float4*)&hsw[2][k];
        const float4 h3 = *(const float4*)&hsw[3][k];
        const float w0 = WP[k * 64 + c];
        const float w1 = WP[(k + 1) * 64 + c];
        const float w2 = WP[(k + 2) * 64 + c];
        const float w3 = WP[(k + 3) * 64 + c];
        s0 = fmaf(h0.x, w0, s0); s0 = fmaf(h0.y, w1, s0); s0 = fmaf(h0.z, w2, s0); s0 = fmaf(h0.w, w3, s0);
        s1 = fmaf(h1.x, w0, s1); s1 = fmaf(h1.y, w1, s1); s1 = fmaf(h1.z, w2, s1); s1 = fmaf(h1.w, w3, s1);
        s2 = fmaf(h2.x, w0, s2); s2 = fmaf(h2.y, w1, s2); s2 = fmaf(h2.z, w2, s2); s2 = fmaf(h2.w, w3, s2);
        s3 = fmaf(h3.x, w0, s3); s3 = fmaf(h3.y, w1, s3); s3 = fmaf(h3.z, w2, s3); s3 = fmaf(h3.w, w3, s3);
    }
    const float bv = BP[c];
    s0 += bv; s1 += bv; s2 += bv; s3 += bv;
    if (relu) { s0 = fmaxf(s0, 0.0f); s1 = fmaxf(s1, 0.0f); s2 = fmaxf(s2, 0.0f); s3 = fmaxf(s3, 0.0f); }
    __syncthreads();
    if (last) {
        gout[(size_t)(n0 + 0) * 64 + c] = s0;
        gout[(size_t)(n0 + 1) * 64 + c] = s1;
        gout[(size_t)(n0 + 2) * 64 + c] = s2;
        gout[(size_t)(n0 + 3) * 64 + c] = s3;
    } else {
        hsw[0][c] = s0; hsw[1][c] = s1; hsw[2][c] = s2; hsw[3][c] = s3;
    }
    __syncthreads();
}

__global__ __launch_bounds__(256) void mlp_kernel(
    const float* __restrict__ x,
    const float* __restrict__ W1, const float* __restrict__ b1,
    const float* __restrict__ W2, const float* __restrict__ b2,
    const float* __restrict__ W3, const float* __restrict__ b3,
    const float* __restrict__ W4, const float* __restrict__ b4,
    const float* __restrict__ Wg1, const float* __restrict__ bg1,
    const float* __restrict__ Wg2, const float* __restrict__ bg2,
    float* __restrict__ g32)
{
    __shared__ float hs[4][4][64];
    const int w = threadIdx.x >> 6;
    const int c = threadIdx.x & 63;
    const int n0 = blockIdx.x * 16 + w * 4;

    float a0 = 0.0f, a1 = 0.0f, a2 = 0.0f, a3 = 0.0f;
    const float* xp = x + (size_t)n0 * IN_DIM;
    #pragma unroll 2
    for (int k = 0; k < IN_DIM; k += 4) {
        const float4 x0 = *(const float4*)(xp + k);
        const float4 x1 = *(const float4*)(xp + IN_DIM + k);
        const float4 x2 = *(const float4*)(xp + 2 * IN_DIM + k);
        const float4 x3 = *(const float4*)(xp + 3 * IN_DIM + k);
        const float w0 = W1[k * 64 + c];
        const float w1 = W1[(k + 1) * 64 + c];
        const float w2 = W1[(k + 2) * 64 + c];
        const float w3 = W1[(k + 3) * 64 + c];
        a0 = fmaf(x0.x, w0, a0); a0 = fmaf(x0.y, w1, a0); a0 = fmaf(x0.z, w2, a0); a0 = fmaf(x0.w, w3, a0);
        a1 = fmaf(x1.x, w0, a1); a1 = fmaf(x1.y, w1, a1); a1 = fmaf(x1.z, w2, a1); a1 = fmaf(x1.w, w3, a1);
        a2 = fmaf(x2.x, w0, a2); a2 = fmaf(x2.y, w1, a2); a2 = fmaf(x2.z, w2, a2); a2 = fmaf(x2.w, w3, a2);
        a3 = fmaf(x3.x, w0, a3); a3 = fmaf(x3.y, w1, a3); a3 = fmaf(x3.z, w2, a3); a3 = fmaf(x3.w, w3, a3);
    }
    const float bv = b1[c];
    hs[w][0][c] = fmaxf(a0 + bv, 0.0f);
    hs[w][1][c] = fmaxf(a1 + bv, 0.0f);
    hs[w][2][c] = fmaxf(a2 + bv, 0.0f);
    hs[w][3][c] = fmaxf(a3 + bv, 0.0f);
    __syncthreads();

    dense_layer32(hs[w], c, W2, b2, false, false, g32, n0);
    dense_layer32(hs[w], c, W3, b3, true,  false, g32, n0);
    dense_layer32(hs[w], c, W4, b4, false, false, g32, n0);
    dense_layer32(hs[w], c, Wg1, bg1, true, false, g32, n0);
    dense_layer32(hs[w], c, Wg2, bg2, false, true, g32, n0);
}

// ---------------- CSR aggregation + finalize (fused): one wave per row ----------------
__global__ __launch_bounds__(256) void aggcsr_kernel(
    const int* __restrict__ offs, const int* __restrict__ ecol_s,
    const float* __restrict__ dinv, const float* __restrict__ g32,
    float* __restrict__ F32, short* __restrict__ Fb)
{
    const int r = (blockIdx.x << 2) + (threadIdx.x >> 6);
    const int h = threadIdx.x & 63;
    const float dr = dinv[r];
    const int b = offs[r], e2 = offs[r + 1];
    long long sum = 0;
    #pragma unroll 8
    for (int i = b; i < e2; ++i) {
        const int cc = ecol_s[i];
        if (cc < 0) continue;
        const float m = __fmul_rn(__fmul_rn(dr, dinv[cc]), g32[((size_t)cc << 6) + h]);
        sum += __double2ll_rn((double)m * AGG_SCALE);
    }
    const float a = (float)((double)sum * AGG_INV);
    const int idx = (r << 6) + h;
    const float f = g32[idx] - a;
    F32[idx] = f;
    __hip_bfloat16 hb = __float2bfloat16(f);
    Fb[idx] = *(short*)&hb;
}

// ---------------- MFMA bf16 screening: LDS-staged B panel, single-barrier pipeline ----------------
// Key: (bits & 0xFFFFC000) ^ (0x80000000 | invcol); globally unique (invcol = 16383-col).
// cand stores the KEYS (u32) so refine can rank globally before gathering.
__device__ __forceinline__ void ins6(unsigned* k, unsigned x) {
    const unsigned r0 = max(k[0], x);
    k[5] = min(k[4], max(k[5], x));
    k[4] = min(k[3], max(k[4], x));
    k[3] = min(k[2], max(k[3], x));
    k[2] = min(k[1], max(k[2], x));
    k[1] = min(k[0], max(k[1], x));
    k[0] = r0;
}

__global__ __launch_bounds__(256) void screen_kernel(
    const short* __restrict__ Fb, unsigned* __restrict__ cand)
{
    __shared__ short Bt[2][128 * 64];   // 2 x 16 KB: [buf][col*64 + swizzled k]
    const int l = threadIdx.x & 63;
    const int w = threadIdx.x >> 6;
    const int rb = blockIdx.x >> 1;
    const int sp = blockIdx.x & 1;
    const int r0 = rb * 64 + w * 16;
    const int c0 = sp * 8192;

    // A fragments: lane l <- Fb[r0 + (l&15)][8*(l>>4) .. +7] and +32
    const short* ap = Fb + ((size_t)(r0 + (l & 15)) << 6) + ((l >> 4) << 3);
    const bf16x8 a0 = *(const bf16x8*)(ap);
    const bf16x8 a1 = *(const bf16x8*)(ap + 32);

    unsigned keys[4][6];
    #pragma unroll
    for (int r = 0; r < 4; ++r)
        #pragma unroll
        for (int t = 0; t < 6; ++t) keys[r][t] = 0u;

    // staging role: col = tid&127, granules jb..jb+3 (64B of the 128B row)
    const int scol = threadIdx.x & 127;
    const int jb = (threadIdx.x >> 7) * 4;
    const short* gsrc0 = Fb + ((size_t)(c0 + scol) << 6) + jb * 8;

    // prologue: stage tile 0; preload tile 1 into st
    bf16x8 st[4];
    #pragma unroll
    for (int j = 0; j < 4; ++j) st[j] = *(const bf16x8*)(gsrc0 + j * 8);
    #pragma unroll
    for (int j = 0; j < 4; ++j)
        *(bf16x8*)(&Bt[0][scol * 64 + (((jb + j) ^ (scol & 7)) << 3)]) = st[j];
    #pragma unroll
    for (int j = 0; j < 4; ++j) st[j] = *(const bf16x8*)(gsrc0 + (1 << 13) + j * 8);
    __syncthreads();

    const unsigned invb = 0x80000000u | (unsigned)(16383 - c0 - (l & 15));
    const int g0 = (l >> 4) ^ (l & 7);
    const int g1 = ((l >> 4) + 4) ^ (l & 7);
    int cur = 0;

    #pragma unroll 1
    for (int t = 0; t < 64; ++t) {
        const short* B = &Bt[cur][0];
        bf16x8 bf[16];
        #pragma unroll
        for (int s = 0; s < 8; ++s) {
            const int C = s * 16 + (l & 15);
            bf[2 * s]     = *(const bf16x8*)(B + C * 64 + (g0 << 3));
            bf[2 * s + 1] = *(const bf16x8*)(B + C * 64 + (g1 << 3));
        }
        if (t + 1 < 64) {
            #pragma unroll
            for (int j = 0; j < 4; ++j)
                *(bf16x8*)(&Bt[cur ^ 1][scol * 64 + (((jb + j) ^ (scol & 7)) << 3)]) = st[j];
        }
        if (t + 2 < 64) {
            const short* gs = gsrc0 + ((size_t)(t + 2) << 13);
            #pragma unroll
            for (int j = 0; j < 4; ++j) st[j] = *(const bf16x8*)(gs + j * 8);
        }
        #pragma unroll
        for (int s = 0; s < 8; ++s) {
            f32x4 acc = {0.0f, 0.0f, 0.0f, 0.0f};
            acc = __builtin_amdgcn_mfma_f32_16x16x32_bf16(a0, bf[2 * s], acc, 0, 0, 0);
            acc = __builtin_amdgcn_mfma_f32_16x16x32_bf16(a1, bf[2 * s + 1], acc, 0, 0, 0);
            const unsigned xv = invb - (unsigned)((t << 7) + (s << 4));
            #pragma unroll
            for (int r = 0; r < 4; ++r) {
                const unsigned key = (__float_as_uint(acc[r]) & 0xFFFFC000u) ^ xv;
                ins6(keys[r], key);
            }
        }
        __syncthreads();   // reads of cur done AND write of cur^1 done
        cur ^= 1;
    }

    #pragma unroll
    for (int r = 0; r < 4; ++r) {
        const int row = r0 + ((l >> 4) << 2) + r;
        unsigned* cp = cand + ((size_t)(sp * N_NODES + row)) * 96 + (l & 15) * 6;
        #pragma unroll
        for (int t = 0; t < 6; ++t) cp[t] = keys[r][t];
    }
}

// ---------------- refine2: bf16-key top-56 cut, then exact f32-chain dots -> stable top-8 ----------------
// Grid-stride 2048 blocks x 8 rows. Per row: select exact 56th-largest key (ballot binary
// search, keys unique), gather only 56 candidate rows (-71% L2 gather traffic), exact dots.
__global__ __launch_bounds__(512) void refine2_kernel(
    const float* __restrict__ F, const unsigned* __restrict__ cand,
    float* __restrict__ out)
{
    __shared__ unsigned skey[192];
    __shared__ int clist[64];
    __shared__ float scand[KKEEP * 68];   // 56*68*4 = 15232 B
    const int t = threadIdx.x;

    #pragma unroll 1
    for (int row = blockIdx.x; row < N_NODES; row += 2048) {
        if (t < 192) {
            const int sp = (t >= 96) ? 1 : 0;
            const int slot = t - 96 * sp;
            skey[t] = cand[((size_t)(sp * N_NODES + row)) * 96 + slot];
        }
        __syncthreads();

        if (t < 64) {
            const unsigned k0 = skey[t], k1 = skey[t + 64], k2 = skey[t + 128];
            unsigned long long lo = 0, hi = 0xFFFFFFFFull;   // count(>=lo)>=K > count(>=hi)
            while (hi - lo > 1) {
                const unsigned mid = (unsigned)((lo + hi) >> 1);
                const int cnt = __popcll(__ballot(k0 >= mid)) +
                                __popcll(__ballot(k1 >= mid)) +
                                __popcll(__ballot(k2 >= mid));
                if (cnt >= KKEEP) lo = mid; else hi = mid;
            }
            const unsigned thr = (unsigned)lo;   // exactly the KKEEP-th largest (keys unique)
            const unsigned long long m0 = __ballot(k0 >= thr);
            const unsigned long long m1 = __ballot(k1 >= thr);
            const unsigned long long m2 = __ballot(k2 >= thr);
            const unsigned long long ltm = (1ull << t) - 1ull;
            const int b1 = __popcll(m0), b2 = b1 + __popcll(m1);
            if (k0 >= thr) clist[__popcll(m0 & ltm)]      = 16383 - (int)(k0 & 0x3FFFu);
            if (k1 >= thr) clist[b1 + __popcll(m1 & ltm)] = 16383 - (int)(k1 & 0x3FFFu);
            if (k2 >= thr) clist[b2 + __popcll(m2 & ltm)] = 16383 - (int)(k2 & 0x3FFFu);
        }
        __syncthreads();

        // gather 56 candidate rows: 8 threads x 32B each = 256B/row, coalesced
        if (t < KKEEP * 8) {
            const int g = t >> 3, sub = t & 7;
            const float* src = F + ((size_t)clist[g] << 6) + sub * 8;
            *(float4*)(&scand[g * 68 + sub * 8])     = *(const float4*)(src);
            *(float4*)(&scand[g * 68 + sub * 8 + 4]) = *(const float4*)(src + 4);
        }
        __syncthreads();

        float val = -3.4e38f; int idx = 1 << 30;
        if (t < KKEEP) {
            idx = clist[t];
            const float* fp = &scand[t * 68];
            const float* frp = F + ((size_t)row << 6);
            float acc = 0.0f;
            #pragma unroll 4
            for (int j = 0; j < 16; ++j) {
                const float4 a = *(const float4*)(frp + 4 * j);   // L1-broadcast global
                const float4 b = *(const float4*)(fp + 4 * j);    // ds_read_b128
                acc = fmaf(a.x, b.x, acc);
                acc = fmaf(a.y, b.y, acc);
                acc = fmaf(a.z, b.z, acc);
                acc = fmaf(a.w, b.w, acc);
            }
            val = acc;
        }
        if (t < 64) {   // wave 0: in-register stable top-8 (val desc, idx asc)
            #pragma unroll 1
            for (int it = 0; it < 8; ++it) {
                float bv = val; int bi = idx;
                #pragma unroll
                for (int off = 32; off > 0; off >>= 1) {
                    const float ov = __shfl_xor(bv, off);
                    const int   oi = __shfl_xor(bi, off);
                    if (ov > bv || (ov == bv && oi < bi)) { bv = ov; bi = oi; }
                }
                if (t == 0) {
                    out[(size_t)row * 8 + it]          = bv;          // topk_vals
                    out[131072 + (size_t)row * 8 + it] = (float)row;  // new_edge_index row 0
                    out[262144 + (size_t)row * 8 + it] = (float)bi;   // new_edge_index row 1
                }
                if (idx == bi) val = -3.4e38f;   // indices unique
            }
        }
        __syncthreads();   // scand/clist free before next row's overwrite
    }
}

__global__ void canary_kernel(float* out, float code) {
    out[0] = code;
}

// ---------------- launch ----------------
extern "C" void kernel_launch(void* const* d_in, const int* in_sizes, int n_in,
                              void* d_out, int out_size, void* d_ws, size_t ws_size,
                              hipStream_t stream)
{
    const float* x   = (const float*)d_in[0];
    const void*  ei  = d_in[1];
    const float* W1  = (const float*)d_in[2];  const float* b1  = (const float*)d_in[3];
    const float* W2  = (const float*)d_in[4];  const float* b2  = (const float*)d_in[5];
    const float* W3  = (const float*)d_in[6];  const float* b3  = (const float*)d_in[7];
    const float* W4  = (const float*)d_in[8];  const float* b4  = (const float*)d_in[9];
    const float* Wg1 = (const float*)d_in[10]; const float* bg1 = (const float*)d_in[11];
    const float* Wg2 = (const float*)d_in[12]; const float* bg2 = (const float*)d_in[13];
    float* out = (float*)d_out;

    // workspace layout (stream-ordered overlays):
    //   g32   [0, 4M)
    //   F32   [4M, 8M)
    //   Fb    [8M, 10M)
    //   cand  [10M, 22M)  -- first 1.1M overlaid by CSR scratch (dead before screen):
    //       ecol_s [10M, 11M), offs [11M, +68K)
    //   deg [23M, +64K) cursor [23M+64K, +128K) (single memset) dinv [23M+128K, +192K)
    char* ws = (char*)d_ws;
    float* g32 = (float*)(ws);
    float* F32 = (float*)(ws + ((size_t)4 << 20));
    short* Fb  = (short*)(ws + ((size_t)8 << 20));
    unsigned* cand = (unsigned*)(ws + ((size_t)10 << 20));
    int*   ecol_s = (int*)(ws + ((size_t)10 << 20));
    int*   offs   = (int*)(ws + ((size_t)11 << 20));
    int*   deg    = (int*)(ws + ((size_t)23 << 20));
    int*   cursor = (int*)(ws + ((size_t)23 << 20) + (1u << 16));
    float* dinvf  = (float*)(ws + ((size_t)23 << 20) + (2u << 16));

    const size_t NEEDED = ((size_t)23 << 20) + (3u << 16);
    if (ws_size < NEEDED || n_in < 14) {
        canary_kernel<<<1, 1, 0, stream>>>(out, ws_size < NEEDED ? 5000.0f : 3000.0f);
        return;
    }

    hipMemsetAsync(deg, 0, 2 * N_NODES * sizeof(int), stream);   // deg + cursor (adjacent)

    deg_kernel<<<E_EDGES / 256, 256, 0, stream>>>(ei, deg);
    scan_kernel<<<1, 256, 0, stream>>>(deg, offs, dinvf);
    scatter_kernel<<<E_EDGES / 256, 256, 0, stream>>>(ei, offs, cursor, ecol_s);
    mlp_kernel<<<N_NODES / 16, 256, 0, stream>>>(x, W1, b1, W2, b2, W3, b3, W4, b4, Wg1, bg1, Wg2, bg2, g32);
    aggcsr_kernel<<<N_NODES / 4, 256, 0, stream>>>(offs, ecol_s, dinvf, g32, F32, Fb);
    screen_kernel<<<512, 256, 0, stream>>>(Fb, cand);
    refine2_kernel<<<2048, 512, 0, stream>>>(F32, cand, out);
}

// Round 22
// 391.351 us; speedup vs baseline: 1.2020x; 1.1432x over previous
//
#include <hip/hip_runtime.h>
#include <hip/hip_bf16.h>

#define N_NODES 16384
#define E_EDGES 262144
#define IN_DIM 512
#define KKEEP 56

// fixed-point scale for deterministic aggregation
#define AGG_SCALE 1099511627776.0   // 2^40
#define AGG_INV   (1.0/1099511627776.0)

typedef __attribute__((ext_vector_type(8))) short bf16x8;
typedef __attribute__((ext_vector_type(4))) float f32x4;

// ---------------- inline edge dtype detection (per-wave uniform) ----------------
__device__ __forceinline__ int detect64(const void* __restrict__ ei) {
    const unsigned long long v = ((const unsigned long long*)ei)[threadIdx.x & 63];
    return __all(v < 16384ull) ? 1 : 0;
}

__device__ __forceinline__ int edge_at(const void* __restrict__ ei, int is64, int pos) {
    return is64 ? (int)(((const long long*)ei)[pos]) : ((const int*)ei)[pos];
}

// ---------------- degree ----------------
__global__ __launch_bounds__(256) void deg_kernel(const void* __restrict__ ei,
                                                  int* __restrict__ deg) {
    const int is64 = detect64(ei);
    int e = blockIdx.x * 256 + threadIdx.x;
    int r = edge_at(ei, is64, e);
    if (r >= 0 && r < N_NODES) atomicAdd(&deg[r], 1);
}

// ---------------- exclusive prefix scan of deg -> offs; also dinv (fused) ----------------
__global__ __launch_bounds__(256) void scan_kernel(const int* __restrict__ deg, int* __restrict__ offs,
                                                   float* __restrict__ dinv) {
    __shared__ int part[257];
    const int t = threadIdx.x;
    const int base = t * 64;
    int s = 0;
    #pragma unroll 4
    for (int i = 0; i < 64; ++i) s += deg[base + i];
    part[t + 1] = s;
    if (t == 0) part[0] = 0;
    __syncthreads();
    if (t == 0) {
        int acc = 0;
        for (int i = 1; i <= 256; ++i) { acc += part[i]; part[i] = acc; }
    }
    __syncthreads();
    int run = part[t];                      // exclusive offset of chunk t
    for (int i = 0; i < 64; ++i) {
        const int d = deg[base + i];
        offs[base + i] = run; run += d;
        dinv[base + i] = (d > 0) ? __fdiv_rn(1.0f, __fsqrt_rn((float)d)) : 0.0f;
    }
    if (t == 255) offs[N_NODES] = run;
}

// ---------------- scatter edges into CSR slots ----------------
__global__ __launch_bounds__(256) void scatter_kernel(
    const void* __restrict__ ei,
    const int* __restrict__ offs, int* __restrict__ cursor, int* __restrict__ ecol_s)
{
    const int is64 = detect64(ei);
    int e = blockIdx.x * 256 + threadIdx.x;
    int r  = edge_at(ei, is64, e);
    if (r < 0 || r >= N_NODES) return;
    int cc = edge_at(ei, is64, E_EDGES + e);
    int pos = atomicAdd(&cursor[r], 1);
    ecol_s[offs[r] + pos] = (cc >= 0 && cc < N_NODES) ? cc : -1;
}

// ---------------- MLP: f32, k-ascending single-accumulator fmaf chains ----------------
__device__ __forceinline__ void dense_layer32(float (*hsw)[64], int c,
                                              const float* __restrict__ WP,
                                              const float* __restrict__ BP,
                                              bool relu, bool last,
                                              float* __restrict__ gout, int n0)
{
    float s0 = 0.0f, s1 = 0.0f, s2 = 0.0f, s3 = 0.0f;
    #pragma unroll 4
    for (int k = 0; k < 64; k += 4) {
        const float4 h0 = *(const float4*)&hsw[0][k];
        const float4 h1 = *(const float4*)&hsw[1][k];
        const float4 h2 = *(const float4*)&hsw[2][k];
        const float4 h3 = *(const float4*)&hsw[3][k];
        const float w0 = WP[k * 64 + c];
        const float w1 = WP[(k + 1) * 64 + c];
        const float w2 = WP[(k + 2) * 64 + c];
        const float w3 = WP[(k + 3) * 64 + c];
        s0 = fmaf(h0.x, w0, s0); s0 = fmaf(h0.y, w1, s0); s0 = fmaf(h0.z, w2, s0); s0 = fmaf(h0.w, w3, s0);
        s1 = fmaf(h1.x, w0, s1); s1 = fmaf(h1.y, w1, s1); s1 = fmaf(h1.z, w2, s1); s1 = fmaf(h1.w, w3, s1);
        s2 = fmaf(h2.x, w0, s2); s2 = fmaf(h2.y, w1, s2); s2 = fmaf(h2.z, w2, s2); s2 = fmaf(h2.w, w3, s2);
        s3 = fmaf(h3.x, w0, s3); s3 = fmaf(h3.y, w1, s3); s3 = fmaf(h3.z, w2, s3); s3 = fmaf(h3.w, w3, s3);
    }
    const float bv = BP[c];
    s0 += bv; s1 += bv; s2 += bv; s3 += bv;
    if (relu) { s0 = fmaxf(s0, 0.0f); s1 = fmaxf(s1, 0.0f); s2 = fmaxf(s2, 0.0f); s3 = fmaxf(s3, 0.0f); }
    __syncthreads();
    if (last) {
        gout[(size_t)(n0 + 0) * 64 + c] = s0;
        gout[(size_t)(n0 + 1) * 64 + c] = s1;
        gout[(size_t)(n0 + 2) * 64 + c] = s2;
        gout[(size_t)(n0 + 3) * 64 + c] = s3;
    } else {
        hsw[0][c] = s0; hsw[1][c] = s1; hsw[2][c] = s2; hsw[3][c] = s3;
    }
    __syncthreads();
}

__global__ __launch_bounds__(256) void mlp_kernel(
    const float* __restrict__ x,
    const float* __restrict__ W1, const float* __restrict__ b1,
    const float* __restrict__ W2, const float* __restrict__ b2,
    const float* __restrict__ W3, const float* __restrict__ b3,
    const float* __restrict__ W4, const float* __restrict__ b4,
    const float* __restrict__ Wg1, const float* __restrict__ bg1,
    const float* __restrict__ Wg2, const float* __restrict__ bg2,
    float* __restrict__ g32)
{
    __shared__ float hs[4][4][64];
    const int w = threadIdx.x >> 6;
    const int c = threadIdx.x & 63;
    const int n0 = blockIdx.x * 16 + w * 4;

    float a0 = 0.0f, a1 = 0.0f, a2 = 0.0f, a3 = 0.0f;
    const float* xp = x + (size_t)n0 * IN_DIM;
    #pragma unroll 2
    for (int k = 0; k < IN_DIM; k += 4) {
        const float4 x0 = *(const float4*)(xp + k);
        const float4 x1 = *(const float4*)(xp + IN_DIM + k);
        const float4 x2 = *(const float4*)(xp + 2 * IN_DIM + k);
        const float4 x3 = *(const float4*)(xp + 3 * IN_DIM + k);
        const float w0 = W1[k * 64 + c];
        const float w1 = W1[(k + 1) * 64 + c];
        const float w2 = W1[(k + 2) * 64 + c];
        const float w3 = W1[(k + 3) * 64 + c];
        a0 = fmaf(x0.x, w0, a0); a0 = fmaf(x0.y, w1, a0); a0 = fmaf(x0.z, w2, a0); a0 = fmaf(x0.w, w3, a0);
        a1 = fmaf(x1.x, w0, a1); a1 = fmaf(x1.y, w1, a1); a1 = fmaf(x1.z, w2, a1); a1 = fmaf(x1.w, w3, a1);
        a2 = fmaf(x2.x, w0, a2); a2 = fmaf(x2.y, w1, a2); a2 = fmaf(x2.z, w2, a2); a2 = fmaf(x2.w, w3, a2);
        a3 = fmaf(x3.x, w0, a3); a3 = fmaf(x3.y, w1, a3); a3 = fmaf(x3.z, w2, a3); a3 = fmaf(x3.w, w3, a3);
    }
    const float bv = b1[c];
    hs[w][0][c] = fmaxf(a0 + bv, 0.0f);
    hs[w][1][c] = fmaxf(a1 + bv, 0.0f);
    hs[w][2][c] = fmaxf(a2 + bv, 0.0f);
    hs[w][3][c] = fmaxf(a3 + bv, 0.0f);
    __syncthreads();

    dense_layer32(hs[w], c, W2, b2, false, false, g32, n0);
    dense_layer32(hs[w], c, W3, b3, true,  false, g32, n0);
    dense_layer32(hs[w], c, W4, b4, false, false, g32, n0);
    dense_layer32(hs[w], c, Wg1, bg1, true, false, g32, n0);
    dense_layer32(hs[w], c, Wg2, bg2, false, true, g32, n0);
}

// ---------------- CSR aggregation + finalize (fused): one wave per row ----------------
__global__ __launch_bounds__(256) void aggcsr_kernel(
    const int* __restrict__ offs, const int* __restrict__ ecol_s,
    const float* __restrict__ dinv, const float* __restrict__ g32,
    float* __restrict__ F32, short* __restrict__ Fb)
{
    const int r = (blockIdx.x << 2) + (threadIdx.x >> 6);
    const int h = threadIdx.x & 63;
    const float dr = dinv[r];
    const int b = offs[r], e2 = offs[r + 1];
    long long sum = 0;
    #pragma unroll 8
    for (int i = b; i < e2; ++i) {
        const int cc = ecol_s[i];
        if (cc < 0) continue;
        const float m = __fmul_rn(__fmul_rn(dr, dinv[cc]), g32[((size_t)cc << 6) + h]);
        sum += __double2ll_rn((double)m * AGG_SCALE);
    }
    const float a = (float)((double)sum * AGG_INV);
    const int idx = (r << 6) + h;
    const float f = g32[idx] - a;
    F32[idx] = f;
    __hip_bfloat16 hb = __float2bfloat16(f);
    Fb[idx] = *(short*)&hb;
}

// ---------------- MFMA bf16 screening: LDS-staged B panel, single-barrier pipeline ----------------
// Key: (bits & 0xFFFFC000) ^ (0x80000000 | invcol); globally unique (invcol = 16383-col).
__device__ __forceinline__ void ins6(unsigned* k, unsigned x) {
    const unsigned r0 = max(k[0], x);
    k[5] = min(k[4], max(k[5], x));
    k[4] = min(k[3], max(k[4], x));
    k[3] = min(k[2], max(k[3], x));
    k[2] = min(k[1], max(k[2], x));
    k[1] = min(k[0], max(k[1], x));
    k[0] = r0;
}

__global__ __launch_bounds__(256) void screen_kernel(
    const short* __restrict__ Fb, unsigned* __restrict__ cand)
{
    __shared__ short Bt[2][128 * 64];   // 2 x 16 KB: [buf][col*64 + swizzled k]
    const int l = threadIdx.x & 63;
    const int w = threadIdx.x >> 6;
    const int rb = blockIdx.x >> 1;
    const int sp = blockIdx.x & 1;
    const int r0 = rb * 64 + w * 16;
    const int c0 = sp * 8192;

    const short* ap = Fb + ((size_t)(r0 + (l & 15)) << 6) + ((l >> 4) << 3);
    const bf16x8 a0 = *(const bf16x8*)(ap);
    const bf16x8 a1 = *(const bf16x8*)(ap + 32);

    unsigned keys[4][6];
    #pragma unroll
    for (int r = 0; r < 4; ++r)
        #pragma unroll
        for (int t = 0; t < 6; ++t) keys[r][t] = 0u;

    const int scol = threadIdx.x & 127;
    const int jb = (threadIdx.x >> 7) * 4;
    const short* gsrc0 = Fb + ((size_t)(c0 + scol) << 6) + jb * 8;

    bf16x8 st[4];
    #pragma unroll
    for (int j = 0; j < 4; ++j) st[j] = *(const bf16x8*)(gsrc0 + j * 8);
    #pragma unroll
    for (int j = 0; j < 4; ++j)
        *(bf16x8*)(&Bt[0][scol * 64 + (((jb + j) ^ (scol & 7)) << 3)]) = st[j];
    #pragma unroll
    for (int j = 0; j < 4; ++j) st[j] = *(const bf16x8*)(gsrc0 + (1 << 13) + j * 8);
    __syncthreads();

    const unsigned invb = 0x80000000u | (unsigned)(16383 - c0 - (l & 15));
    const int g0 = (l >> 4) ^ (l & 7);
    const int g1 = ((l >> 4) + 4) ^ (l & 7);
    int cur = 0;

    #pragma unroll 1
    for (int t = 0; t < 64; ++t) {
        const short* B = &Bt[cur][0];
        bf16x8 bf[16];
        #pragma unroll
        for (int s = 0; s < 8; ++s) {
            const int C = s * 16 + (l & 15);
            bf[2 * s]     = *(const bf16x8*)(B + C * 64 + (g0 << 3));
            bf[2 * s + 1] = *(const bf16x8*)(B + C * 64 + (g1 << 3));
        }
        if (t + 1 < 64) {
            #pragma unroll
            for (int j = 0; j < 4; ++j)
                *(bf16x8*)(&Bt[cur ^ 1][scol * 64 + (((jb + j) ^ (scol & 7)) << 3)]) = st[j];
        }
        if (t + 2 < 64) {
            const short* gs = gsrc0 + ((size_t)(t + 2) << 13);
            #pragma unroll
            for (int j = 0; j < 4; ++j) st[j] = *(const bf16x8*)(gs + j * 8);
        }
        #pragma unroll
        for (int s = 0; s < 8; ++s) {
            f32x4 acc = {0.0f, 0.0f, 0.0f, 0.0f};
            acc = __builtin_amdgcn_mfma_f32_16x16x32_bf16(a0, bf[2 * s], acc, 0, 0, 0);
            acc = __builtin_amdgcn_mfma_f32_16x16x32_bf16(a1, bf[2 * s + 1], acc, 0, 0, 0);
            const unsigned xv = invb - (unsigned)((t << 7) + (s << 4));
            #pragma unroll
            for (int r = 0; r < 4; ++r) {
                const unsigned key = (__float_as_uint(acc[r]) & 0xFFFFC000u) ^ xv;
                ins6(keys[r], key);
            }
        }
        __syncthreads();
        cur ^= 1;
    }

    #pragma unroll
    for (int r = 0; r < 4; ++r) {
        const int row = r0 + ((l >> 4) << 2) + r;
        unsigned* cp = cand + ((size_t)(sp * N_NODES + row)) * 96 + (l & 15) * 6;
        #pragma unroll
        for (int t = 0; t < 6; ++t) cp[t] = keys[r][t];
    }
}

// ---------------- refine2: dual-row halves + key prefetch; bf16-key top-56 cut; exact dots ----------------
// 1024 blocks x 512 threads; halves (256 thr) each own one row per iteration (2 rows in
// flight); next iteration's keys prefetched into registers (hides HBM latency).
__global__ __launch_bounds__(512) void refine2_kernel(
    const float* __restrict__ F, const unsigned* __restrict__ cand,
    float* __restrict__ out)
{
    __shared__ unsigned skey[2][192];
    __shared__ int clist[2][64];
    __shared__ float scand[2][KKEEP * 68];   // 2 x 15232 B
    const int tid = threadIdx.x;
    const int half = tid >> 8;
    const int th = tid & 255;

    // key slot for this thread (th<192): split sp, slot
    const int ksp = (th >= 96) ? 1 : 0;
    const int kslot = th - 96 * ksp;

    // prologue: prefetch iteration 0 keys
    unsigned kreg = 0u;
    {
        const int row0 = blockIdx.x * 2 + half;
        if (th < 192) kreg = cand[((size_t)(ksp * N_NODES + row0)) * 96 + kslot];
    }

    #pragma unroll 1
    for (int i = 0; i < 8; ++i) {
        const int row = blockIdx.x * 2 + half + i * 2048;
        if (th < 192) skey[half][th] = kreg;
        __syncthreads();   // skey visible; prev iter's scand readers (dot) done

        // prefetch next iteration's keys (HBM latency overlaps this whole row)
        if (i + 1 < 8 && th < 192)
            kreg = cand[((size_t)(ksp * N_NODES + (row + 2048))) * 96 + kslot];

        // wave-local exact top-KKEEP selection (th<64 is a full wave in both halves)
        if (th < 64) {
            const unsigned k0 = skey[half][th], k1 = skey[half][th + 64], k2 = skey[half][th + 128];
            unsigned long long lo = 0, hi = 0xFFFFFFFFull;
            while (hi - lo > 1) {
                const unsigned mid = (unsigned)((lo + hi) >> 1);
                const int cnt = __popcll(__ballot(k0 >= mid)) +
                                __popcll(__ballot(k1 >= mid)) +
                                __popcll(__ballot(k2 >= mid));
                if (cnt >= KKEEP) lo = mid; else hi = mid;
            }
            const unsigned thr = (unsigned)lo;   // exact KKEEP-th largest (keys unique)
            const unsigned long long m0 = __ballot(k0 >= thr);
            const unsigned long long m1 = __ballot(k1 >= thr);
            const unsigned long long m2 = __ballot(k2 >= thr);
            const unsigned long long ltm = (1ull << th) - 1ull;
            const int b1 = __popcll(m0), b2 = b1 + __popcll(m1);
            if (k0 >= thr) clist[half][__popcll(m0 & ltm)]      = 16383 - (int)(k0 & 0x3FFFu);
            if (k1 >= thr) clist[half][b1 + __popcll(m1 & ltm)] = 16383 - (int)(k1 & 0x3FFFu);
            if (k2 >= thr) clist[half][b2 + __popcll(m2 & ltm)] = 16383 - (int)(k2 & 0x3FFFu);
        }
        __syncthreads();   // clist visible

        // gather 56 candidate rows: 4 threads x 64B each
        if (th < KKEEP * 4) {
            const int g = th >> 2, sub = th & 3;
            const float* src = F + ((size_t)clist[half][g] << 6) + sub * 16;
            float* dst = &scand[half][g * 68 + sub * 16];
            #pragma unroll
            for (int j = 0; j < 4; ++j)
                *(float4*)(dst + 4 * j) = *(const float4*)(src + 4 * j);
        }
        __syncthreads();   // scand ready

        // exact f32-chain dots + in-wave stable top-8 (wave 0 of the half)
        float val = -3.4e38f; int idx = 1 << 30;
        if (th < KKEEP) {
            idx = clist[half][th];
            const float* fp = &scand[half][th * 68];
            const float* frp = F + ((size_t)row << 6);
            float acc = 0.0f;
            #pragma unroll 4
            for (int j = 0; j < 16; ++j) {
                const float4 a = *(const float4*)(frp + 4 * j);
                const float4 b = *(const float4*)(fp + 4 * j);
                acc = fmaf(a.x, b.x, acc);
                acc = fmaf(a.y, b.y, acc);
                acc = fmaf(a.z, b.z, acc);
                acc = fmaf(a.w, b.w, acc);
            }
            val = acc;
        }
        if (th < 64) {
            #pragma unroll 1
            for (int it = 0; it < 8; ++it) {
                float bv = val; int bi = idx;
                #pragma unroll
                for (int off = 32; off > 0; off >>= 1) {
                    const float ov = __shfl_xor(bv, off);
                    const int   oi = __shfl_xor(bi, off);
                    if (ov > bv || (ov == bv && oi < bi)) { bv = ov; bi = oi; }
                }
                if (th == 0) {
                    out[(size_t)row * 8 + it]          = bv;          // topk_vals
                    out[131072 + (size_t)row * 8 + it] = (float)row;  // src row
                    out[262144 + (size_t)row * 8 + it] = (float)bi;   // topk_idx
                }
                if (idx == bi) val = -3.4e38f;
            }
        }
        // no trailing barrier: next iteration's top barrier orders scand/skey reuse
    }
}

__global__ void canary_kernel(float* out, float code) {
    out[0] = code;
}

// ---------------- launch ----------------
extern "C" void kernel_launch(void* const* d_in, const int* in_sizes, int n_in,
                              void* d_out, int out_size, void* d_ws, size_t ws_size,
                              hipStream_t stream)
{
    const float* x   = (const float*)d_in[0];
    const void*  ei  = d_in[1];
    const float* W1  = (const float*)d_in[2];  const float* b1  = (const float*)d_in[3];
    const float* W2  = (const float*)d_in[4];  const float* b2  = (const float*)d_in[5];
    const float* W3  = (const float*)d_in[6];  const float* b3  = (const float*)d_in[7];
    const float* W4  = (const float*)d_in[8];  const float* b4  = (const float*)d_in[9];
    const float* Wg1 = (const float*)d_in[10]; const float* bg1 = (const float*)d_in[11];
    const float* Wg2 = (const float*)d_in[12]; const float* bg2 = (const float*)d_in[13];
    float* out = (float*)d_out;

    // workspace layout (stream-ordered overlays):
    //   g32   [0, 4M)
    //   F32   [4M, 8M)
    //   Fb    [8M, 10M)
    //   cand  [10M, 22M)  -- first 1.1M overlaid by CSR scratch (dead before screen):
    //       ecol_s [10M, 11M), offs [11M, +68K)
    //   deg [23M, +64K) cursor [23M+64K, +128K) (single memset) dinv [23M+128K, +192K)
    char* ws = (char*)d_ws;
    float* g32 = (float*)(ws);
    float* F32 = (float*)(ws + ((size_t)4 << 20));
    short* Fb  = (short*)(ws + ((size_t)8 << 20));
    unsigned* cand = (unsigned*)(ws + ((size_t)10 << 20));
    int*   ecol_s = (int*)(ws + ((size_t)10 << 20));
    int*   offs   = (int*)(ws + ((size_t)11 << 20));
    int*   deg    = (int*)(ws + ((size_t)23 << 20));
    int*   cursor = (int*)(ws + ((size_t)23 << 20) + (1u << 16));
    float* dinvf  = (float*)(ws + ((size_t)23 << 20) + (2u << 16));

    const size_t NEEDED = ((size_t)23 << 20) + (3u << 16);
    if (ws_size < NEEDED || n_in < 14) {
        canary_kernel<<<1, 1, 0, stream>>>(out, ws_size < NEEDED ? 5000.0f : 3000.0f);
        return;
    }

    hipMemsetAsync(deg, 0, 2 * N_NODES * sizeof(int), stream);   // deg + cursor (adjacent)

    deg_kernel<<<E_EDGES / 256, 256, 0, stream>>>(ei, deg);
    scan_kernel<<<1, 256, 0, stream>>>(deg, offs, dinvf);
    scatter_kernel<<<E_EDGES / 256, 256, 0, stream>>>(ei, offs, cursor, ecol_s);
    mlp_kernel<<<N_NODES / 16, 256, 0, stream>>>(x, W1, b1, W2, b2, W3, b3, W4, b4, Wg1, bg1, Wg2, bg2, g32);
    aggcsr_kernel<<<N_NODES / 4, 256, 0, stream>>>(offs, ecol_s, dinvf, g32, F32, Fb);
    screen_kernel<<<512, 256, 0, stream>>>(Fb, cand);
    refine2_kernel<<<1024, 512, 0, stream>>>(F32, cand, out);
}